// Round 2
// baseline (230.977 us; speedup 1.0000x reference)
//
#include <hip/hip_runtime.h>
#include <hip/hip_bf16.h>

// MsPAM+CAM fused, MI355X gfx950.  B=2, C=64, H=W=64, N=4096, Cq=8.
// Device dtype (f32 vs bf16) detected at runtime (flag in ws); math f32/MFMA.

typedef __attribute__((ext_vector_type(8))) short bf16x8;
typedef __attribute__((ext_vector_type(4))) float f32x4;

#define MFMA16(a, b, c) __builtin_amdgcn_mfma_f32_16x16x32_bf16(a, b, c, 0, 0, 0)

__device__ __forceinline__ float bf2f(ushort u) {
  union { unsigned int i; float f; } v; v.i = ((unsigned int)u) << 16; return v.f;
}
__device__ __forceinline__ ushort f2bf(float f) {  // RNE
  union { float f; unsigned int i; } v; v.f = f;
  unsigned int r = v.i + 0x7FFFu + ((v.i >> 16) & 1u);
  return (ushort)(r >> 16);
}
__device__ __forceinline__ float loadf(const void* p, size_t i, int isbf) {
  return isbf ? bf2f(((const ushort*)p)[i]) : ((const float*)p)[i];
}
__device__ __forceinline__ bf16x8 load8(const void* p, size_t i, int isbf) {
  if (isbf) return *(const bf16x8*)((const ushort*)p + i);
  const float* f = (const float*)p + i;
  bf16x8 r;
#pragma unroll
  for (int j = 0; j < 8; ++j) r[j] = (short)f2bf(f[j]);
  return r;
}

// ---------------------------------------------------------------------------
// K0: dtype detect. If bf16-packed, low16 of each u32 is a bf16 ~N(0,1):
// exponent bits (w>>7)&0xFF land in [120,133] ~95%. If f32: uniform (~5%) or 0.
__global__ void k_detect(const unsigned int* __restrict__ x, int* __restrict__ flag) {
  if (threadIdx.x == 0 && blockIdx.x == 0) {
    int hits = 0;
    for (int i = 0; i < 128; ++i) {
      unsigned int e = (x[i] >> 7) & 0xFFu;
      hits += (e >= 120u && e <= 133u) ? 1 : 0;
    }
    *flag = (hits > 64) ? 1 : 0;
  }
}

// ---------------------------------------------------------------------------
// K1: Q,K1,K2,K3 1x1 convs -> padded transposed tables QT[b][m][32], KT[b*3+br][n][32].
__global__ __launch_bounds__(256) void k_prep_qk(
    const void* __restrict__ x, const void* __restrict__ y, const void* __restrict__ z,
    const void* __restrict__ wq, const void* __restrict__ bq,
    const void* __restrict__ wk1, const void* __restrict__ bk1,
    const void* __restrict__ wk2, const void* __restrict__ bk2,
    const void* __restrict__ wk3, const void* __restrict__ bk3,
    ushort* __restrict__ QT, ushort* __restrict__ KT, const int* __restrict__ flagp)
{
  int isbf = *flagp;
  __shared__ float wsh[4][8][64];
  int t = threadIdx.x;
  for (int i = t; i < 4 * 512; i += 256) {
    int mat = i >> 9, rem = i & 511;
    const void* src = (mat == 0) ? wq : (mat == 1) ? wk1 : (mat == 2) ? wk2 : wk3;
    wsh[mat][rem >> 6][rem & 63] = loadf(src, rem, isbf);
  }
  __syncthreads();

  int gid = blockIdx.x * 256 + t;
  int n = gid & 4095, b = gid >> 12;
  float q[8] = {0}, k1[8] = {0}, k2[8] = {0}, k3[8] = {0};
  size_t base = (size_t)b * 262144 + n;
  for (int c = 0; c < 64; ++c) {
    float xv = loadf(x, base + (size_t)c * 4096, isbf);
    float yv = loadf(y, base + (size_t)c * 4096, isbf);
    float zv = loadf(z, base + (size_t)c * 4096, isbf);
#pragma unroll
    for (int o = 0; o < 8; ++o) {
      q[o]  += wsh[0][o][c] * xv;
      k1[o] += wsh[1][o][c] * xv;
      k2[o] += wsh[2][o][c] * yv;
      k3[o] += wsh[3][o][c] * zv;
    }
  }
  ushort* qrow  = QT + (size_t)(b * 4096 + n) * 32;
  ushort* k1row = KT + (size_t)((b * 3 + 0) * 4096 + n) * 32;
  ushort* k2row = KT + (size_t)((b * 3 + 1) * 4096 + n) * 32;
  ushort* k3row = KT + (size_t)((b * 3 + 2) * 4096 + n) * 32;
#pragma unroll
  for (int o = 0; o < 8; ++o) {
    qrow[o]  = f2bf(q[o]  + loadf(bq, o, isbf));
    k1row[o] = f2bf(k1[o] + loadf(bk1, o, isbf));
    k2row[o] = f2bf(k2[o] + loadf(bk2, o, isbf));
    k3row[o] = f2bf(k3[o] + loadf(bk3, o, isbf));
  }
#pragma unroll
  for (int o = 8; o < 32; ++o) { qrow[o] = 0; k1row[o] = 0; k2row[o] = 0; k3row[o] = 0; }
}

// ---------------------------------------------------------------------------
// K2: V = wv*x + bv, V[b][c][m] bf16.
__global__ __launch_bounds__(256) void k_prep_v(
    const void* __restrict__ x, const void* __restrict__ wv,
    const void* __restrict__ bv, ushort* __restrict__ V, const int* __restrict__ flagp)
{
  int isbf = *flagp;
  int tid = blockIdx.x * 256 + threadIdx.x;
  int m = tid & 4095, c = (tid >> 12) & 63, b = tid >> 18;
  float acc = loadf(bv, c, isbf);
  size_t xb = (size_t)b * 262144 + m;
  for (int d = 0; d < 64; ++d)
    acc += loadf(wv, c * 64 + d, isbf) * loadf(x, xb + (size_t)d * 4096, isbf);
  V[tid] = f2bf(acc);
}

// ---------------------------------------------------------------------------
// K3: CAM gram partials e_part[b][k][ns][64][64] f32.
__global__ __launch_bounds__(256) void k_cam_gram(
    const void* __restrict__ x, const void* __restrict__ y, const void* __restrict__ z,
    float* __restrict__ e_part, const int* __restrict__ flagp)
{
  int isbf = *flagp;
  int blk = blockIdx.x;
  int b = blk / 24, r = blk % 24, k = r >> 3, ns = r & 7;
  const void* A = x;
  const void* B = (k == 0) ? x : (k == 1) ? y : z;
  size_t boff = (size_t)b * 262144;
  int w = threadIdx.x >> 6, l = threadIdx.x & 63;
  int l15 = l & 15, lh = l >> 4;
  int cbase = 16 * w;
  f32x4 acc[4];
#pragma unroll
  for (int i = 0; i < 4; ++i) acc[i] = (f32x4){0.f, 0.f, 0.f, 0.f};
  int n0 = ns * 512;
  for (int step = 0; step < 16; ++step) {
    int nb = n0 + step * 32;
    bf16x8 af = load8(A, boff + (size_t)(cbase + l15) * 4096 + nb + lh * 8, isbf);
#pragma unroll
    for (int dt = 0; dt < 4; ++dt) {
      bf16x8 bfr = load8(B, boff + (size_t)(dt * 16 + l15) * 4096 + nb + lh * 8, isbf);
      acc[dt] = MFMA16(af, bfr, acc[dt]);
    }
  }
  float* out = e_part + (size_t)(((b * 3 + k) * 8 + ns) * 64) * 64;
#pragma unroll
  for (int dt = 0; dt < 4; ++dt)
#pragma unroll
    for (int rr = 0; rr < 4; ++rr) {
      int c = cbase + lh * 4 + rr, d = dt * 16 + l15;
      out[c * 64 + d] = acc[dt][rr];
    }
}

// ---------------------------------------------------------------------------
// K4: PAM pass 1 — invS[b][br][m] = 1 / sum_n exp(E[m,n]).
__global__ __launch_bounds__(256) void k_pam_s(
    const ushort* __restrict__ QT, const ushort* __restrict__ KT, float* __restrict__ invS)
{
  int blk = blockIdx.x;
  int mc = blk & 63, br = (blk >> 6) % 3, b = blk / 192;
  int w = threadIdx.x >> 6, l = threadIdx.x & 63;
  int l15 = l & 15, lh = l >> 4;
  int mbase = mc * 64 + w * 16;
  bf16x8 qf = *(const bf16x8*)(QT + (size_t)(b * 4096 + mbase + l15) * 32 + lh * 8);
  const ushort* Kb = KT + (size_t)((b * 3 + br) * 4096 + l15) * 32 + lh * 8;
  float s = 0.f;
#pragma unroll 4
  for (int ns = 0; ns < 256; ++ns) {
    bf16x8 kf = *(const bf16x8*)(Kb + (size_t)ns * 512);
    f32x4 d = MFMA16(kf, qf, ((f32x4){0.f, 0.f, 0.f, 0.f}));
    s += __expf(d[0]) + __expf(d[1]) + __expf(d[2]) + __expf(d[3]);
  }
  s += __shfl_xor(s, 16, 64);
  s += __shfl_xor(s, 32, 64);
  if (l < 16) invS[(b * 3 + br) * 4096 + mbase + l] = 1.0f / s;
}

// ---------------------------------------------------------------------------
// K5: CAM small — Atot = sum_k softmax_row(-e_k); Wfull=[gc*Wc*Atot | gp*Wp]; biasv.
__global__ __launch_bounds__(256) void k_cam_small(
    const float* __restrict__ e_part,
    const void* __restrict__ cam_wl, const void* __restrict__ cam_bl, const void* __restrict__ cam_gamma,
    const void* __restrict__ pam_wl, const void* __restrict__ pam_bl, const void* __restrict__ pam_gamma,
    ushort* __restrict__ Wfull, float* __restrict__ biasv, const int* __restrict__ flagp)
{
  int isbf = *flagp;
  int b = blockIdx.x, t = threadIdx.x;
  __shared__ float Atot[64][64];
  __shared__ float erow[64][64];
  for (int i = t; i < 4096; i += 256) ((float*)Atot)[i] = 0.f;
  __syncthreads();
  for (int k = 0; k < 3; ++k) {
    for (int i = t; i < 4096; i += 256) {
      const float* ep = e_part + (size_t)((b * 3 + k) * 8) * 4096 + i;
      float s = 0.f;
#pragma unroll
      for (int ks = 0; ks < 8; ++ks) s += ep[ks * 4096];
      ((float*)erow)[i] = s;
    }
    __syncthreads();
    if (t < 64) {  // softmax(max-e) == exp(mn-e)/sum(exp(mn-e))
      float mn = erow[t][0];
      for (int d = 1; d < 64; ++d) mn = fminf(mn, erow[t][d]);
      float s = 0.f;
      for (int d = 0; d < 64; ++d) s += __expf(mn - erow[t][d]);
      float inv = 1.0f / s;
      for (int d = 0; d < 64; ++d) Atot[t][d] += __expf(mn - erow[t][d]) * inv;
    }
    __syncthreads();
  }
  float gc = loadf(cam_gamma, 0, isbf), gp = loadf(pam_gamma, 0, isbf);
  int c = t >> 2, d0 = (t & 3) * 16;
  float a[16];
#pragma unroll
  for (int i = 0; i < 16; ++i) a[i] = 0.f;
  for (int e = 0; e < 64; ++e) {
    float wv = loadf(cam_wl, c * 64 + e, isbf);
#pragma unroll
    for (int i = 0; i < 16; ++i) a[i] += wv * Atot[e][d0 + i];
  }
#pragma unroll
  for (int i = 0; i < 16; ++i) {
    int d = d0 + i;
    Wfull[(size_t)(b * 64 + c) * 128 + d]      = f2bf(gc * a[i]);
    Wfull[(size_t)(b * 64 + c) * 128 + 64 + d] = f2bf(gp * loadf(pam_wl, c * 64 + d, isbf));
  }
  if (b == 0 && t < 64) biasv[t] = gp * loadf(pam_bl, t, isbf) + gc * loadf(cam_bl, t, isbf);
}

// ---------------------------------------------------------------------------
// K6: PAM pass 2 — pam_part[b][ms][c][n] (bf16) = sum_{m slice} V[c,m]*Ptot[m,n].
__global__ __launch_bounds__(256) void k_pam_out(
    const ushort* __restrict__ QT, const ushort* __restrict__ KT, const ushort* __restrict__ V,
    const float* __restrict__ invS, ushort* __restrict__ pam_part)
{
  __shared__ ushort plds[64 * 64];
  int blk = blockIdx.x;
  int ms = blk & 3, nt = (blk >> 2) & 63, b = blk >> 8;
  int w = threadIdx.x >> 6, l = threadIdx.x & 63;
  int l15 = l & 15, lh = l >> 4;
  int n0 = nt * 64;

  bf16x8 kf[3];
#pragma unroll
  for (int br = 0; br < 3; ++br)
    kf[br] = *(const bf16x8*)(KT + (size_t)((b * 3 + br) * 4096 + n0 + 16 * w + l15) * 32 + lh * 8);
  const float* iS = invS + b * 3 * 4096;

  f32x4 acc[4];
#pragma unroll
  for (int i = 0; i < 4; ++i) acc[i] = (f32x4){0.f, 0.f, 0.f, 0.f};

  for (int ch = 0; ch < 16; ++ch) {
    int m0 = ms * 1024 + ch * 64;
#pragma unroll
    for (int mt = 0; mt < 4; ++mt) {
      bf16x8 qf = *(const bf16x8*)(QT + (size_t)(b * 4096 + m0 + mt * 16 + l15) * 32 + lh * 8);
      f32x4 d0 = MFMA16(kf[0], qf, ((f32x4){0.f, 0.f, 0.f, 0.f}));
      f32x4 d1 = MFMA16(kf[1], qf, ((f32x4){0.f, 0.f, 0.f, 0.f}));
      f32x4 d2 = MFMA16(kf[2], qf, ((f32x4){0.f, 0.f, 0.f, 0.f}));
      int mg = m0 + mt * 16 + l15;
      float i0 = iS[mg], i1 = iS[4096 + mg], i2 = iS[8192 + mg];
#pragma unroll
      for (int r = 0; r < 4; ++r) {
        float p = __expf(d0[r]) * i0 + __expf(d1[r]) * i1 + __expf(d2[r]) * i2;
        int nl = 16 * w + lh * 4 + r;
        int byte = (nl * 128 + (mt * 16 + l15) * 2) ^ ((nl & 7) << 4);
        *(ushort*)((char*)plds + byte) = f2bf(p);
      }
    }
    __syncthreads();
#pragma unroll
    for (int ks = 0; ks < 2; ++ks) {
      bf16x8 vf = *(const bf16x8*)(V + (size_t)(b * 64 + 16 * w + l15) * 4096 + m0 + ks * 32 + lh * 8);
#pragma unroll
      for (int nt4 = 0; nt4 < 4; ++nt4) {
        int nl = nt4 * 16 + l15;
        int byte = (nl * 128 + (ks * 32 + lh * 8) * 2) ^ ((nl & 7) << 4);
        bf16x8 pf = *(const bf16x8*)((const char*)plds + byte);
        acc[nt4] = MFMA16(vf, pf, acc[nt4]);
      }
    }
    __syncthreads();
  }
  ushort* out = pam_part + (size_t)((b * 4 + ms) * 64) * 4096;
#pragma unroll
  for (int nt4 = 0; nt4 < 4; ++nt4)
#pragma unroll
    for (int r = 0; r < 4; ++r) {
      int c = 16 * w + lh * 4 + r, n = n0 + nt4 * 16 + l15;
      out[(size_t)c * 4096 + n] = f2bf(acc[nt4][r]);
    }
}

// ---------------------------------------------------------------------------
// K7: final — out = 2x + M_b*x + (gp*Wp)*pam_out + biasv.
__global__ __launch_bounds__(256) void k_final(
    const void* __restrict__ x, const ushort* __restrict__ pam_part,
    const ushort* __restrict__ Wfull, const float* __restrict__ biasv,
    void* __restrict__ outv, const int* __restrict__ flagp)
{
  int isbf = *flagp;
  __shared__ ushort u[64 * 128];
  int blk = blockIdx.x;
  int nt = blk & 63, b = blk >> 6;
  int t = threadIdx.x;
  int n0 = nt * 64;
  int d = t >> 2, nl0 = (t & 3) * 16;
  size_t xbase = (size_t)(b * 64 + d) * 4096 + n0 + nl0;
#pragma unroll
  for (int i = 0; i < 16; ++i) {
    int nl = nl0 + i;
    int byte = (nl * 256 + d * 2) ^ ((nl & 7) << 4);
    *(ushort*)((char*)u + byte) = f2bf(loadf(x, xbase + i, isbf));
  }
  const ushort* pp = pam_part + (size_t)(b * 256 + d) * 4096 + n0 + nl0;
#pragma unroll
  for (int i = 0; i < 16; ++i) {
    float s = bf2f(pp[i]) + bf2f(pp[262144 + i]) + bf2f(pp[524288 + i]) + bf2f(pp[786432 + i]);
    int nl = nl0 + i;
    int byte = (nl * 256 + (64 + d) * 2) ^ ((nl & 7) << 4);
    *(ushort*)((char*)u + byte) = f2bf(s);
  }
  __syncthreads();

  int w = t >> 6, l = t & 63, l15 = l & 15, lh = l >> 4;
  f32x4 acc[4];
#pragma unroll
  for (int i = 0; i < 4; ++i) acc[i] = (f32x4){0.f, 0.f, 0.f, 0.f};
#pragma unroll
  for (int ks = 0; ks < 4; ++ks) {
    bf16x8 af = *(const bf16x8*)(Wfull + (size_t)(b * 64 + 16 * w + l15) * 128 + ks * 32 + lh * 8);
#pragma unroll
    for (int nt4 = 0; nt4 < 4; ++nt4) {
      int nl = nt4 * 16 + l15;
      int byte = (nl * 256 + (ks * 32 + lh * 8) * 2) ^ ((nl & 7) << 4);
      bf16x8 bfr = *(const bf16x8*)((const char*)u + byte);
      acc[nt4] = MFMA16(af, bfr, acc[nt4]);
    }
  }
#pragma unroll
  for (int nt4 = 0; nt4 < 4; ++nt4)
#pragma unroll
    for (int r = 0; r < 4; ++r) {
      int c = 16 * w + lh * 4 + r, nl = nt4 * 16 + l15;
      size_t xidx = (size_t)(b * 64 + c) * 4096 + n0 + nl;
      float xv = loadf(x, xidx, isbf);
      float v = acc[nt4][r] + 2.0f * xv + biasv[c];
      if (isbf) ((ushort*)outv)[xidx] = f2bf(v);
      else      ((float*)outv)[xidx]  = v;
    }
}

// ---------------------------------------------------------------------------
extern "C" void kernel_launch(void* const* d_in, const int* in_sizes, int n_in,
                              void* d_out, int out_size, void* d_ws, size_t ws_size,
                              hipStream_t stream) {
  const void* x   = d_in[0];
  const void* y   = d_in[1];
  const void* z   = d_in[2];
  const void* wq  = d_in[3];
  const void* bq  = d_in[4];
  const void* wk1 = d_in[5];
  const void* bk1 = d_in[6];
  const void* wk2 = d_in[7];
  const void* bk2 = d_in[8];
  const void* wk3 = d_in[9];
  const void* bk3 = d_in[10];
  const void* wv  = d_in[11];
  const void* bv  = d_in[12];
  const void* pwl = d_in[13];
  const void* pbl = d_in[14];
  const void* pg  = d_in[15];
  const void* cwl = d_in[16];
  const void* cbl = d_in[17];
  const void* cg  = d_in[18];

  char* ws = (char*)d_ws;
  int*    flag    = (int*)   (ws + 0);          //  4 B (pad 256)
  ushort* QT      = (ushort*)(ws + 256);        //  512 KB  [2][4096][32] bf16
  ushort* KT      = (ushort*)(ws + 524544);     // 1536 KB  [6][4096][32] bf16
  ushort* V       = (ushort*)(ws + 2097408);    // 1024 KB  [2][64][4096] bf16
  float*  invS    = (float*) (ws + 3145984);    //   96 KB  [2][3][4096] f32
  float*  e_part  = (float*) (ws + 3244288);    // 3072 KB  [2][3][8][64][64] f32
  ushort* pam_prt = (ushort*)(ws + 6390016);    // 4096 KB  [2][4][64][4096] bf16
  ushort* Wfull   = (ushort*)(ws + 10584320);   //   32 KB  [2][64][128] bf16
  float*  biasv   = (float*) (ws + 10617088);   //  256 B   [64] f32

  k_detect  <<<   1,  64, 0, stream>>>((const unsigned int*)x, flag);
  k_prep_qk <<<  32, 256, 0, stream>>>(x, y, z, wq, bq, wk1, bk1, wk2, bk2, wk3, bk3, QT, KT, flag);
  k_prep_v  <<<2048, 256, 0, stream>>>(x, wv, bv, V, flag);
  k_cam_gram<<<  48, 256, 0, stream>>>(x, y, z, e_part, flag);
  k_pam_s   <<< 384, 256, 0, stream>>>(QT, KT, invS);
  k_cam_small<<<  2, 256, 0, stream>>>(e_part, cwl, cbl, cg, pwl, pbl, pg, Wfull, biasv, flag);
  k_pam_out <<< 512, 256, 0, stream>>>(QT, KT, V, invS, pam_prt);
  k_final   <<< 128, 256, 0, stream>>>(x, pam_prt, Wfull, biasv, d_out, flag);
}

// Round 3
// 160.509 us; speedup vs baseline: 1.4390x; 1.4390x over previous
//
#include <hip/hip_runtime.h>
#include <hip/hip_bf16.h>

// MsPAM+CAM fused, MI355X gfx950.  B=2, C=64, H=W=64, N=4096, Cq=8.
// Runtime dtype detect (f32 vs bf16). Softmax normalization folded into MFMA
// via spare Q/K slots (Q slots 8..13 = -log2(S) split, K slots one-hot 1.0).

typedef __attribute__((ext_vector_type(8))) short bf16x8;
typedef __attribute__((ext_vector_type(4))) float f32x4;

#define MFMA16(a, b, c) __builtin_amdgcn_mfma_f32_16x16x32_bf16(a, b, c, 0, 0, 0)
#define EX2(x) __builtin_amdgcn_exp2f(x)
#define LOG2E 1.4426950408889634f

__device__ __forceinline__ float bf2f(ushort u) {
  union { unsigned int i; float f; } v; v.i = ((unsigned int)u) << 16; return v.f;
}
__device__ __forceinline__ ushort f2bf(float f) {  // RNE
  union { float f; unsigned int i; } v; v.f = f;
  unsigned int r = v.i + 0x7FFFu + ((v.i >> 16) & 1u);
  return (ushort)(r >> 16);
}
__device__ __forceinline__ float loadf(const void* p, size_t i, int isbf) {
  return isbf ? bf2f(((const ushort*)p)[i]) : ((const float*)p)[i];
}
__device__ __forceinline__ bf16x8 load8(const void* p, size_t i, int isbf) {
  if (isbf) return *(const bf16x8*)((const ushort*)p + i);
  const float* f = (const float*)p + i;
  bf16x8 r;
#pragma unroll
  for (int j = 0; j < 8; ++j) r[j] = (short)f2bf(f[j]);
  return r;
}

// ---------------------------------------------------------------------------
// K0: dtype detect (one wave).
__global__ void k_detect(const unsigned int* __restrict__ x, int* __restrict__ flag) {
  int l = threadIdx.x;
  unsigned int w1 = x[l], w2 = x[64 + l];
  unsigned int e1 = (w1 >> 7) & 0xFFu, e2 = (w2 >> 7) & 0xFFu;
  unsigned long long b1 = __ballot(e1 >= 120u && e1 <= 133u);
  unsigned long long b2 = __ballot(e2 >= 120u && e2 <= 133u);
  if (l == 0) *flag = (__popcll(b1) + __popcll(b2) > 64) ? 1 : 0;
}

// ---------------------------------------------------------------------------
// K1: Q,K1,K2,K3 1x1 convs -> QT[b][m][32] (q scaled by log2e; slots 8..31 = 0),
//     KT[b*3+br][n][32] (slots 8+2br,9+2br = 1.0, rest of 8..31 = 0).
// 4 threads per n (c-split 16 each) + quad shfl reduce. 128 blocks.
__global__ __launch_bounds__(256) void k_prep_qk(
    const void* __restrict__ x, const void* __restrict__ y, const void* __restrict__ z,
    const void* __restrict__ wq, const void* __restrict__ bq,
    const void* __restrict__ wk1, const void* __restrict__ bk1,
    const void* __restrict__ wk2, const void* __restrict__ bk2,
    const void* __restrict__ wk3, const void* __restrict__ bk3,
    ushort* __restrict__ QT, ushort* __restrict__ KT, const int* __restrict__ flagp)
{
  int isbf = *flagp;
  __shared__ float wsh[4][8][64];
  int t = threadIdx.x;
  for (int i = t; i < 2048; i += 256) {
    int mat = i >> 9, rem = i & 511;
    const void* src = (mat == 0) ? wq : (mat == 1) ? wk1 : (mat == 2) ? wk2 : wk3;
    wsh[mat][rem >> 6][rem & 63] = loadf(src, rem, isbf);
  }
  __syncthreads();

  int gid = blockIdx.x * 256 + t;       // 0..32767
  int qid = gid & 3;
  int n = (gid >> 2) & 4095;
  int b = gid >> 14;
  int c0 = qid * 16;
  float a[4][8];
#pragma unroll
  for (int m = 0; m < 4; ++m)
#pragma unroll
    for (int o = 0; o < 8; ++o) a[m][o] = 0.f;
  size_t base = (size_t)b * 262144 + n;
  for (int cc = 0; cc < 16; ++cc) {
    int c = c0 + cc;
    float xv = loadf(x, base + (size_t)c * 4096, isbf);
    float yv = loadf(y, base + (size_t)c * 4096, isbf);
    float zv = loadf(z, base + (size_t)c * 4096, isbf);
#pragma unroll
    for (int o = 0; o < 8; ++o) {
      a[0][o] += wsh[0][o][c] * xv;
      a[1][o] += wsh[1][o][c] * xv;
      a[2][o] += wsh[2][o][c] * yv;
      a[3][o] += wsh[3][o][c] * zv;
    }
  }
#pragma unroll
  for (int m = 0; m < 4; ++m)
#pragma unroll
    for (int o = 0; o < 8; ++o) {
      float v = a[m][o];
      v += __shfl_xor(v, 1, 64);
      v += __shfl_xor(v, 2, 64);
      a[m][o] = v;
    }
  int br = qid - 1;
  const void* bias = (qid == 0) ? bq : (qid == 1) ? bk1 : (qid == 2) ? bk2 : bk3;
  ushort* dst = (qid == 0) ? QT + (size_t)(b * 4096 + n) * 32
                           : KT + (size_t)((b * 3 + br) * 4096 + n) * 32;
  ushort row[32];
#pragma unroll
  for (int o = 0; o < 8; ++o) {
    float v = a[qid][o] + loadf(bias, o, isbf);
    row[o] = f2bf(qid == 0 ? LOG2E * v : v);
  }
#pragma unroll
  for (int o = 8; o < 32; ++o)
    row[o] = (qid > 0 && (o == 8 + 2 * br || o == 9 + 2 * br)) ? (ushort)0x3F80 : (ushort)0;
#pragma unroll
  for (int o = 0; o < 32; o += 2)
    *(unsigned int*)(dst + o) = (unsigned int)row[o] | ((unsigned int)row[o + 1] << 16);
}

// ---------------------------------------------------------------------------
// K2: V = wv*x + bv, V[b][c][m] bf16.
__global__ __launch_bounds__(256) void k_prep_v(
    const void* __restrict__ x, const void* __restrict__ wv,
    const void* __restrict__ bv, ushort* __restrict__ V, const int* __restrict__ flagp)
{
  int isbf = *flagp;
  int tid = blockIdx.x * 256 + threadIdx.x;
  int m = tid & 4095, c = (tid >> 12) & 63, b = tid >> 18;
  float acc = loadf(bv, c, isbf);
  size_t xb = (size_t)b * 262144 + m;
  for (int d = 0; d < 64; ++d)
    acc += loadf(wv, c * 64 + d, isbf) * loadf(x, xb + (size_t)d * 4096, isbf);
  V[tid] = f2bf(acc);
}

// ---------------------------------------------------------------------------
// K3: CAM gram partials e_part[b][k][ns16][64][64] f32 (256 n per slice). 96 blocks.
__global__ __launch_bounds__(256) void k_cam_gram(
    const void* __restrict__ x, const void* __restrict__ y, const void* __restrict__ z,
    float* __restrict__ e_part, const int* __restrict__ flagp)
{
  int isbf = *flagp;
  int blk = blockIdx.x;
  int ns = blk & 15, r = blk >> 4;      // r in 0..5
  int k = r % 3, b = r / 3;
  const void* A = x;
  const void* B = (k == 0) ? x : (k == 1) ? y : z;
  size_t boff = (size_t)b * 262144;
  int w = threadIdx.x >> 6, l = threadIdx.x & 63;
  int l15 = l & 15, lh = l >> 4;
  int cbase = 16 * w;
  f32x4 acc[4];
#pragma unroll
  for (int i = 0; i < 4; ++i) acc[i] = (f32x4){0.f, 0.f, 0.f, 0.f};
  int n0 = ns * 256;
  for (int step = 0; step < 8; ++step) {
    int nb = n0 + step * 32;
    bf16x8 af = load8(A, boff + (size_t)(cbase + l15) * 4096 + nb + lh * 8, isbf);
#pragma unroll
    for (int dt = 0; dt < 4; ++dt) {
      bf16x8 bfr = load8(B, boff + (size_t)(dt * 16 + l15) * 4096 + nb + lh * 8, isbf);
      acc[dt] = MFMA16(af, bfr, acc[dt]);
    }
  }
  float* out = e_part + (size_t)(((b * 3 + k) * 16 + ns) * 64) * 64;
#pragma unroll
  for (int dt = 0; dt < 4; ++dt)
#pragma unroll
    for (int rr = 0; rr < 4; ++rr) {
      int c = cbase + lh * 4 + rr, d = dt * 16 + l15;
      out[c * 64 + d] = acc[dt][rr];
    }
}

// ---------------------------------------------------------------------------
// K4: PAM pass 1 — S_part[sl][(b*3+br)*4096+m] = sum_{n slice} exp2(Ehat). 1536 blocks.
__global__ __launch_bounds__(256) void k_pam_s(
    const ushort* __restrict__ QT, const ushort* __restrict__ KT, float* __restrict__ S_part)
{
  int blk = blockIdx.x;
  int sl = blk & 3, mc = (blk >> 2) & 63, r3 = blk >> 8;  // r3 in 0..5
  int br = r3 % 3, b = r3 / 3;
  int w = threadIdx.x >> 6, l = threadIdx.x & 63;
  int l15 = l & 15, lh = l >> 4;
  int mbase = mc * 64 + w * 16;
  bf16x8 qf = *(const bf16x8*)(QT + (size_t)(b * 4096 + mbase + l15) * 32 + lh * 8);
  const ushort* Kb = KT + (size_t)((b * 3 + br) * 4096) * 32;
  float s = 0.f;
  int ns0 = sl * 64;
#pragma unroll 4
  for (int ns = ns0; ns < ns0 + 64; ++ns) {
    bf16x8 kf = *(const bf16x8*)(Kb + (size_t)(ns * 16 + l15) * 32 + lh * 8);
    f32x4 d = MFMA16(kf, qf, ((f32x4){0.f, 0.f, 0.f, 0.f}));
    s += EX2(d[0]) + EX2(d[1]) + EX2(d[2]) + EX2(d[3]);
  }
  s += __shfl_xor(s, 16, 64);
  s += __shfl_xor(s, 32, 64);
  if (l < 16) S_part[sl * 24576 + (b * 3 + br) * 4096 + mbase + l] = s;
}

// ---------------------------------------------------------------------------
// K4b: finalize — L = log2(sum partials); QT slots 8+2br,9+2br = -L (coarse+resid).
__global__ __launch_bounds__(256) void k_s_final(
    const float* __restrict__ S_part, ushort* __restrict__ QT)
{
  int i = blockIdx.x * 256 + threadIdx.x;   // 24576
  float S = S_part[i] + S_part[24576 + i] + S_part[49152 + i] + S_part[73728 + i];
  float nL = -__builtin_amdgcn_logf(S);     // -log2(S)
  int m = i & 4095, b3br = i >> 12;
  int br = b3br % 3, b = b3br / 3;
  ushort c = f2bf(nL);
  ushort r = f2bf(nL - bf2f(c));
  ushort* qrow = QT + (size_t)(b * 4096 + m) * 32;
  qrow[8 + 2 * br] = c;
  qrow[9 + 2 * br] = r;
}

// ---------------------------------------------------------------------------
// K5: CAM small — Atot = sum_k softmax_row(-e_k); Wfull=[gc*Wc*Atot | gp*Wp]; biasv.
__global__ __launch_bounds__(256) void k_cam_small(
    const float* __restrict__ e_part,
    const void* __restrict__ cam_wl, const void* __restrict__ cam_bl, const void* __restrict__ cam_gamma,
    const void* __restrict__ pam_wl, const void* __restrict__ pam_bl, const void* __restrict__ pam_gamma,
    ushort* __restrict__ Wfull, float* __restrict__ biasv, const int* __restrict__ flagp)
{
  int isbf = *flagp;
  int b = blockIdx.x, t = threadIdx.x;
  __shared__ float Atot[64][64];
  __shared__ float erow[64][64];
  for (int i = t; i < 4096; i += 256) ((float*)Atot)[i] = 0.f;
  __syncthreads();
  for (int k = 0; k < 3; ++k) {
    for (int i = t; i < 4096; i += 256) {
      const float* ep = e_part + (size_t)((b * 3 + k) * 16) * 4096 + i;
      float s = 0.f;
#pragma unroll
      for (int ks = 0; ks < 16; ++ks) s += ep[ks * 4096];
      ((float*)erow)[i] = s;
    }
    __syncthreads();
    if (t < 64) {
      float mn = erow[t][0];
      for (int d = 1; d < 64; ++d) mn = fminf(mn, erow[t][d]);
      float s = 0.f;
      for (int d = 0; d < 64; ++d) s += __expf(mn - erow[t][d]);
      float inv = 1.0f / s;
      for (int d = 0; d < 64; ++d) Atot[t][d] += __expf(mn - erow[t][d]) * inv;
    }
    __syncthreads();
  }
  float gc = loadf(cam_gamma, 0, isbf), gp = loadf(pam_gamma, 0, isbf);
  int c = t >> 2, d0 = (t & 3) * 16;
  float a[16];
#pragma unroll
  for (int i = 0; i < 16; ++i) a[i] = 0.f;
  for (int e = 0; e < 64; ++e) {
    float wv = loadf(cam_wl, c * 64 + e, isbf);
#pragma unroll
    for (int i = 0; i < 16; ++i) a[i] += wv * Atot[e][d0 + i];
  }
#pragma unroll
  for (int i = 0; i < 16; ++i) {
    int d = d0 + i;
    Wfull[(size_t)(b * 64 + c) * 128 + d]      = f2bf(gc * a[i]);
    Wfull[(size_t)(b * 64 + c) * 128 + 64 + d] = f2bf(gp * loadf(pam_wl, c * 64 + d, isbf));
  }
  if (b == 0 && t < 64) biasv[t] = gp * loadf(pam_bl, t, isbf) + gc * loadf(cam_bl, t, isbf);
}

// ---------------------------------------------------------------------------
// K6: PAM pass 2 — pam_part[b][ms][c][n] = sum_{m slice} V[c,m]*P[m,n],
//     P = sum_br exp2(Ehat_br - L_br) via L-slots in QT/KT. 1024 blocks (n-tile 32).
__global__ __launch_bounds__(256) void k_pam_out(
    const ushort* __restrict__ QT, const ushort* __restrict__ KT, const ushort* __restrict__ V,
    ushort* __restrict__ pam_part)
{
  __shared__ ushort plds[32 * 64];   // [n 32][m 64], XOR-swizzled rows
  int blk = blockIdx.x;
  int ms = blk & 3, nt = (blk >> 2) & 127, b = blk >> 9;
  int w = threadIdx.x >> 6, l = threadIdx.x & 63;
  int l15 = l & 15, lh = l >> 4;
  int n0 = nt * 32;

  bf16x8 kf[3][2];
#pragma unroll
  for (int br = 0; br < 3; ++br)
#pragma unroll
    for (int n16 = 0; n16 < 2; ++n16)
      kf[br][n16] = *(const bf16x8*)(KT + (size_t)((b * 3 + br) * 4096 + n0 + n16 * 16 + l15) * 32 + lh * 8);

  f32x4 acc[2];
  acc[0] = (f32x4){0.f, 0.f, 0.f, 0.f};
  acc[1] = (f32x4){0.f, 0.f, 0.f, 0.f};
  const ushort* Vb = V + (size_t)(b * 64 + 16 * w + l15) * 4096;

  for (int ch = 0; ch < 16; ++ch) {
    int mch = ms * 1024 + ch * 64;
    bf16x8 qf = *(const bf16x8*)(QT + (size_t)(b * 4096 + mch + 16 * w + l15) * 32 + lh * 8);
#pragma unroll
    for (int n16 = 0; n16 < 2; ++n16) {
      f32x4 d0 = MFMA16(qf, kf[0][n16], ((f32x4){0.f, 0.f, 0.f, 0.f}));
      f32x4 d1 = MFMA16(qf, kf[1][n16], ((f32x4){0.f, 0.f, 0.f, 0.f}));
      f32x4 d2 = MFMA16(qf, kf[2][n16], ((f32x4){0.f, 0.f, 0.f, 0.f}));
      unsigned int u0, u1;
      {
        float p0 = EX2(d0[0]) + EX2(d1[0]) + EX2(d2[0]);
        float p1 = EX2(d0[1]) + EX2(d1[1]) + EX2(d2[1]);
        float p2 = EX2(d0[2]) + EX2(d1[2]) + EX2(d2[2]);
        float p3 = EX2(d0[3]) + EX2(d1[3]) + EX2(d2[3]);
        u0 = (unsigned int)f2bf(p0) | ((unsigned int)f2bf(p1) << 16);
        u1 = (unsigned int)f2bf(p2) | ((unsigned int)f2bf(p3) << 16);
      }
      int nl = n16 * 16 + l15;
      int byte = (nl * 128 + (16 * w + lh * 4) * 2) ^ ((nl & 7) << 4);
      *(uint2*)((char*)plds + byte) = make_uint2(u0, u1);
    }
    __syncthreads();
#pragma unroll
    for (int ks = 0; ks < 2; ++ks) {
      bf16x8 vf = *(const bf16x8*)(Vb + mch + ks * 32 + lh * 8);
#pragma unroll
      for (int n16 = 0; n16 < 2; ++n16) {
        int nl = n16 * 16 + l15;
        int byte = (nl * 128 + (ks * 32 + lh * 8) * 2) ^ ((nl & 7) << 4);
        bf16x8 pf = *(const bf16x8*)((const char*)plds + byte);
        acc[n16] = MFMA16(vf, pf, acc[n16]);
      }
    }
    __syncthreads();
  }
  ushort* outp = pam_part + (size_t)((b * 4 + ms) * 64) * 4096;
#pragma unroll
  for (int n16 = 0; n16 < 2; ++n16)
#pragma unroll
    for (int r = 0; r < 4; ++r) {
      int c = 16 * w + lh * 4 + r, n = n0 + n16 * 16 + l15;
      outp[(size_t)c * 4096 + n] = f2bf(acc[n16][r]);
    }
}

// ---------------------------------------------------------------------------
// K7: final — out = 2x + M_b*x + (gp*Wp)*pam_out + biasv.
__global__ __launch_bounds__(256) void k_final(
    const void* __restrict__ x, const ushort* __restrict__ pam_part,
    const ushort* __restrict__ Wfull, const float* __restrict__ biasv,
    void* __restrict__ outv, const int* __restrict__ flagp)
{
  int isbf = *flagp;
  __shared__ ushort u[64 * 128];
  int blk = blockIdx.x;
  int nt = blk & 63, b = blk >> 6;
  int t = threadIdx.x;
  int n0 = nt * 64;
  int d = t >> 2, nl0 = (t & 3) * 16;
  size_t xbase = (size_t)(b * 64 + d) * 4096 + n0 + nl0;
#pragma unroll
  for (int i = 0; i < 16; ++i) {
    int nl = nl0 + i;
    int byte = (nl * 256 + d * 2) ^ ((nl & 7) << 4);
    *(ushort*)((char*)u + byte) = f2bf(loadf(x, xbase + i, isbf));
  }
  const ushort* pp = pam_part + (size_t)(b * 256 + d) * 4096 + n0 + nl0;
#pragma unroll
  for (int i = 0; i < 16; ++i) {
    float s = bf2f(pp[i]) + bf2f(pp[262144 + i]) + bf2f(pp[524288 + i]) + bf2f(pp[786432 + i]);
    int nl = nl0 + i;
    int byte = (nl * 256 + (64 + d) * 2) ^ ((nl & 7) << 4);
    *(ushort*)((char*)u + byte) = f2bf(s);
  }
  __syncthreads();

  int w = t >> 6, l = t & 63, l15 = l & 15, lh = l >> 4;
  f32x4 acc[4];
#pragma unroll
  for (int i = 0; i < 4; ++i) acc[i] = (f32x4){0.f, 0.f, 0.f, 0.f};
#pragma unroll
  for (int ks = 0; ks < 4; ++ks) {
    bf16x8 af = *(const bf16x8*)(Wfull + (size_t)(b * 64 + 16 * w + l15) * 128 + ks * 32 + lh * 8);
#pragma unroll
    for (int nt4 = 0; nt4 < 4; ++nt4) {
      int nl = nt4 * 16 + l15;
      int byte = (nl * 256 + (ks * 32 + lh * 8) * 2) ^ ((nl & 7) << 4);
      bf16x8 bfr = *(const bf16x8*)((const char*)u + byte);
      acc[nt4] = MFMA16(af, bfr, acc[nt4]);
    }
  }
#pragma unroll
  for (int nt4 = 0; nt4 < 4; ++nt4)
#pragma unroll
    for (int r = 0; r < 4; ++r) {
      int c = 16 * w + lh * 4 + r, nl = nt4 * 16 + l15;
      size_t xidx = (size_t)(b * 64 + c) * 4096 + n0 + nl;
      float xv = loadf(x, xidx, isbf);
      float v = acc[nt4][r] + 2.0f * xv + biasv[c];
      if (isbf) ((ushort*)outv)[xidx] = f2bf(v);
      else      ((float*)outv)[xidx]  = v;
    }
}

// ---------------------------------------------------------------------------
extern "C" void kernel_launch(void* const* d_in, const int* in_sizes, int n_in,
                              void* d_out, int out_size, void* d_ws, size_t ws_size,
                              hipStream_t stream) {
  const void* x   = d_in[0];
  const void* y   = d_in[1];
  const void* z   = d_in[2];
  const void* wq  = d_in[3];
  const void* bq  = d_in[4];
  const void* wk1 = d_in[5];
  const void* bk1 = d_in[6];
  const void* wk2 = d_in[7];
  const void* bk2 = d_in[8];
  const void* wk3 = d_in[9];
  const void* bk3 = d_in[10];
  const void* wv  = d_in[11];
  const void* bv  = d_in[12];
  const void* pwl = d_in[13];
  const void* pbl = d_in[14];
  const void* pg  = d_in[15];
  const void* cwl = d_in[16];
  const void* cbl = d_in[17];
  const void* cg  = d_in[18];

  char* ws = (char*)d_ws;
  int*    flag    = (int*)   (ws + 0);          //  4 B (pad 256)
  ushort* QT      = (ushort*)(ws + 256);        //  512 KB  [2][4096][32] bf16
  ushort* KT      = (ushort*)(ws + 524544);     // 1536 KB  [6][4096][32] bf16
  ushort* V       = (ushort*)(ws + 2097408);    // 1024 KB  [2][64][4096] bf16
  float*  S_part  = (float*) (ws + 3145984);    //  384 KB  [4][2*3*4096] f32
  float*  e_part  = (float*) (ws + 3539200);    // 1536 KB  [2][3][16][64][64] f32
  ushort* pam_prt = (ushort*)(ws + 5112064);    // 4096 KB  [2][4][64][4096] bf16
  ushort* Wfull   = (ushort*)(ws + 9306368);    //   32 KB  [2][64][128] bf16
  float*  biasv   = (float*) (ws + 9339136);    //  256 B   [64] f32

  k_detect   <<<   1,  64, 0, stream>>>((const unsigned int*)x, flag);
  k_prep_qk  <<< 128, 256, 0, stream>>>(x, y, z, wq, bq, wk1, bk1, wk2, bk2, wk3, bk3, QT, KT, flag);
  k_prep_v   <<<2048, 256, 0, stream>>>(x, wv, bv, V, flag);
  k_cam_gram <<<  96, 256, 0, stream>>>(x, y, z, e_part, flag);
  k_pam_s    <<<1536, 256, 0, stream>>>(QT, KT, S_part);
  k_s_final  <<<  96, 256, 0, stream>>>(S_part, QT);
  k_cam_small<<<   2, 256, 0, stream>>>(e_part, cwl, cbl, cg, pwl, pbl, pg, Wfull, biasv, flag);
  k_pam_out  <<<1024, 256, 0, stream>>>(QT, KT, V, pam_prt);
  k_final    <<< 128, 256, 0, stream>>>(x, pam_prt, Wfull, biasv, d_out, flag);
}

// Round 4
// 131.992 us; speedup vs baseline: 1.7499x; 1.2160x over previous
//
#include <hip/hip_runtime.h>
#include <hip/hip_bf16.h>

// MsPAM+CAM fused, MI355X gfx950.  B=2, C=64, H=W=64, N=4096, Cq=8.
// Runtime dtype detect (f32 vs bf16). Softmax normalization folded into MFMA
// via spare Q/K slots (Q slots 8..13 = -log2(S) split, K slots one-hot 1.0).

typedef __attribute__((ext_vector_type(8))) short bf16x8;
typedef __attribute__((ext_vector_type(4))) float f32x4;

#define MFMA16(a, b, c) __builtin_amdgcn_mfma_f32_16x16x32_bf16(a, b, c, 0, 0, 0)
#define EX2(x) __builtin_amdgcn_exp2f(x)
#define LOG2E 1.4426950408889634f

__device__ __forceinline__ float bf2f(ushort u) {
  union { unsigned int i; float f; } v; v.i = ((unsigned int)u) << 16; return v.f;
}
__device__ __forceinline__ ushort f2bf(float f) {  // RNE
  union { float f; unsigned int i; } v; v.f = f;
  unsigned int r = v.i + 0x7FFFu + ((v.i >> 16) & 1u);
  return (ushort)(r >> 16);
}
__device__ __forceinline__ float loadf(const void* p, size_t i, int isbf) {
  return isbf ? bf2f(((const ushort*)p)[i]) : ((const float*)p)[i];
}
__device__ __forceinline__ bf16x8 load8(const void* p, size_t i, int isbf) {
  if (isbf) return *(const bf16x8*)((const ushort*)p + i);
  const float* f = (const float*)p + i;
  bf16x8 r;
#pragma unroll
  for (int j = 0; j < 8; ++j) r[j] = (short)f2bf(f[j]);
  return r;
}

// ---------------------------------------------------------------------------
// K0: dtype detect (one wave).
__global__ void k_detect(const unsigned int* __restrict__ x, int* __restrict__ flag) {
  int l = threadIdx.x;
  unsigned int w1 = x[l], w2 = x[64 + l];
  unsigned int e1 = (w1 >> 7) & 0xFFu, e2 = (w2 >> 7) & 0xFFu;
  unsigned long long b1 = __ballot(e1 >= 120u && e1 <= 133u);
  unsigned long long b2 = __ballot(e2 >= 120u && e2 <= 133u);
  if (l == 0) *flag = (__popcll(b1) + __popcll(b2) > 64) ? 1 : 0;
}

// ---------------------------------------------------------------------------
// K1: Q,K1,K2,K3 1x1 convs -> QT[b][m][32] (q scaled by log2e; slots 8..31 = 0),
//     KT[b*3+br][n][32] (slots 8+2br,9+2br = 1.0, rest of 8..31 = 0).
__global__ __launch_bounds__(256) void k_prep_qk(
    const void* __restrict__ x, const void* __restrict__ y, const void* __restrict__ z,
    const void* __restrict__ wq, const void* __restrict__ bq,
    const void* __restrict__ wk1, const void* __restrict__ bk1,
    const void* __restrict__ wk2, const void* __restrict__ bk2,
    const void* __restrict__ wk3, const void* __restrict__ bk3,
    ushort* __restrict__ QT, ushort* __restrict__ KT, const int* __restrict__ flagp)
{
  int isbf = *flagp;
  __shared__ float wsh[4][8][64];
  int t = threadIdx.x;
  for (int i = t; i < 2048; i += 256) {
    int mat = i >> 9, rem = i & 511;
    const void* src = (mat == 0) ? wq : (mat == 1) ? wk1 : (mat == 2) ? wk2 : wk3;
    wsh[mat][rem >> 6][rem & 63] = loadf(src, rem, isbf);
  }
  __syncthreads();

  int gid = blockIdx.x * 256 + t;       // 0..32767
  int qid = gid & 3;
  int n = (gid >> 2) & 4095;
  int b = gid >> 14;
  int c0 = qid * 16;
  float a[4][8];
#pragma unroll
  for (int m = 0; m < 4; ++m)
#pragma unroll
    for (int o = 0; o < 8; ++o) a[m][o] = 0.f;
  size_t base = (size_t)b * 262144 + n;
  for (int cc = 0; cc < 16; ++cc) {
    int c = c0 + cc;
    float xv = loadf(x, base + (size_t)c * 4096, isbf);
    float yv = loadf(y, base + (size_t)c * 4096, isbf);
    float zv = loadf(z, base + (size_t)c * 4096, isbf);
#pragma unroll
    for (int o = 0; o < 8; ++o) {
      a[0][o] += wsh[0][o][c] * xv;
      a[1][o] += wsh[1][o][c] * xv;
      a[2][o] += wsh[2][o][c] * yv;
      a[3][o] += wsh[3][o][c] * zv;
    }
  }
#pragma unroll
  for (int m = 0; m < 4; ++m)
#pragma unroll
    for (int o = 0; o < 8; ++o) {
      float v = a[m][o];
      v += __shfl_xor(v, 1, 64);
      v += __shfl_xor(v, 2, 64);
      a[m][o] = v;
    }
  int br = qid - 1;
  const void* bias = (qid == 0) ? bq : (qid == 1) ? bk1 : (qid == 2) ? bk2 : bk3;
  ushort* dst = (qid == 0) ? QT + (size_t)(b * 4096 + n) * 32
                           : KT + (size_t)((b * 3 + br) * 4096 + n) * 32;
  ushort row[32];
#pragma unroll
  for (int o = 0; o < 8; ++o) {
    float v = a[qid][o] + loadf(bias, o, isbf);
    row[o] = f2bf(qid == 0 ? LOG2E * v : v);
  }
#pragma unroll
  for (int o = 8; o < 32; ++o)
    row[o] = (qid > 0 && (o == 8 + 2 * br || o == 9 + 2 * br)) ? (ushort)0x3F80 : (ushort)0;
#pragma unroll
  for (int o = 0; o < 32; o += 2)
    *(unsigned int*)(dst + o) = (unsigned int)row[o] | ((unsigned int)row[o + 1] << 16);
}

// ---------------------------------------------------------------------------
// K2: V = wv*x + bv, V[b][c][m] bf16.
__global__ __launch_bounds__(256) void k_prep_v(
    const void* __restrict__ x, const void* __restrict__ wv,
    const void* __restrict__ bv, ushort* __restrict__ V, const int* __restrict__ flagp)
{
  int isbf = *flagp;
  int tid = blockIdx.x * 256 + threadIdx.x;
  int m = tid & 4095, c = (tid >> 12) & 63, b = tid >> 18;
  float acc = loadf(bv, c, isbf);
  size_t xb = (size_t)b * 262144 + m;
  for (int d = 0; d < 64; ++d)
    acc += loadf(wv, c * 64 + d, isbf) * loadf(x, xb + (size_t)d * 4096, isbf);
  V[tid] = f2bf(acc);
}

// ---------------------------------------------------------------------------
// K3: CAM gram partials e_part[b][k][ns16][64][64] f32 (256 n per slice). 96 blocks.
__global__ __launch_bounds__(256) void k_cam_gram(
    const void* __restrict__ x, const void* __restrict__ y, const void* __restrict__ z,
    float* __restrict__ e_part, const int* __restrict__ flagp)
{
  int isbf = *flagp;
  int blk = blockIdx.x;
  int ns = blk & 15, r = blk >> 4;      // r in 0..5
  int k = r % 3, b = r / 3;
  const void* A = x;
  const void* B = (k == 0) ? x : (k == 1) ? y : z;
  size_t boff = (size_t)b * 262144;
  int w = threadIdx.x >> 6, l = threadIdx.x & 63;
  int l15 = l & 15, lh = l >> 4;
  int cbase = 16 * w;
  f32x4 acc[4];
#pragma unroll
  for (int i = 0; i < 4; ++i) acc[i] = (f32x4){0.f, 0.f, 0.f, 0.f};
  int n0 = ns * 256;
  for (int step = 0; step < 8; ++step) {
    int nb = n0 + step * 32;
    bf16x8 af = load8(A, boff + (size_t)(cbase + l15) * 4096 + nb + lh * 8, isbf);
#pragma unroll
    for (int dt = 0; dt < 4; ++dt) {
      bf16x8 bfr = load8(B, boff + (size_t)(dt * 16 + l15) * 4096 + nb + lh * 8, isbf);
      acc[dt] = MFMA16(af, bfr, acc[dt]);
    }
  }
  float* out = e_part + (size_t)(((b * 3 + k) * 16 + ns) * 64) * 64;
#pragma unroll
  for (int dt = 0; dt < 4; ++dt)
#pragma unroll
    for (int rr = 0; rr < 4; ++rr) {
      int c = cbase + lh * 4 + rr, d = dt * 16 + l15;
      out[c * 64 + d] = acc[dt][rr];
    }
}

// ---------------------------------------------------------------------------
// K3b: reduce gram partials -> e_red[b][k][64][64] f32. 96 blocks.
__global__ __launch_bounds__(256) void k_cam_reduce(
    const float* __restrict__ e_part, float* __restrict__ e_red)
{
  int i = blockIdx.x * 256 + threadIdx.x;   // 24576
  int cd = i & 4095, bk = i >> 12;
  const float* p = e_part + (size_t)bk * 65536 + cd;
  float s = 0.f;
#pragma unroll
  for (int ks = 0; ks < 16; ++ks) s += p[ks * 4096];
  e_red[i] = s;
}

// ---------------------------------------------------------------------------
// K4: PAM pass 1 — S_part[sl][(b*3+br)*4096+m] = sum_{n slice} exp2(Ehat). 1536 blocks.
__global__ __launch_bounds__(256) void k_pam_s(
    const ushort* __restrict__ QT, const ushort* __restrict__ KT, float* __restrict__ S_part)
{
  int blk = blockIdx.x;
  int sl = blk & 3, mc = (blk >> 2) & 63, r3 = blk >> 8;  // r3 in 0..5
  int br = r3 % 3, b = r3 / 3;
  int w = threadIdx.x >> 6, l = threadIdx.x & 63;
  int l15 = l & 15, lh = l >> 4;
  int mbase = mc * 64 + w * 16;
  bf16x8 qf = *(const bf16x8*)(QT + (size_t)(b * 4096 + mbase + l15) * 32 + lh * 8);
  const ushort* Kb = KT + (size_t)((b * 3 + br) * 4096) * 32;
  float s = 0.f;
  int ns0 = sl * 64;
#pragma unroll 4
  for (int ns = ns0; ns < ns0 + 64; ++ns) {
    bf16x8 kf = *(const bf16x8*)(Kb + (size_t)(ns * 16 + l15) * 32 + lh * 8);
    f32x4 d = MFMA16(kf, qf, ((f32x4){0.f, 0.f, 0.f, 0.f}));
    s += EX2(d[0]) + EX2(d[1]) + EX2(d[2]) + EX2(d[3]);
  }
  s += __shfl_xor(s, 16, 64);
  s += __shfl_xor(s, 32, 64);
  if (l < 16) S_part[sl * 24576 + (b * 3 + br) * 4096 + mbase + l] = s;
}

// ---------------------------------------------------------------------------
// K4b: finalize — L = log2(sum partials); QT slots 8+2br,9+2br = -L (coarse+resid).
__global__ __launch_bounds__(256) void k_s_final(
    const float* __restrict__ S_part, ushort* __restrict__ QT)
{
  int i = blockIdx.x * 256 + threadIdx.x;   // 24576
  float S = S_part[i] + S_part[24576 + i] + S_part[49152 + i] + S_part[73728 + i];
  float nL = -__builtin_amdgcn_logf(S);     // -log2(S)
  int m = i & 4095, b3br = i >> 12;
  int br = b3br % 3, b = b3br / 3;
  ushort c = f2bf(nL);
  ushort r = f2bf(nL - bf2f(c));
  ushort* qrow = QT + (size_t)(b * 4096 + m) * 32;
  qrow[8 + 2 * br] = c;
  qrow[9 + 2 * br] = r;
}

// ---------------------------------------------------------------------------
// K5: CAM small — parallel softmax (4 threads/row), Atot = sum_k softmax_row(-e_k);
//     Wfull=[gc*Wc*Atot | gp*Wp]; biasv. 2 blocks.
__global__ __launch_bounds__(256) void k_cam_small(
    const float* __restrict__ e_red,
    const void* __restrict__ cam_wl, const void* __restrict__ cam_bl, const void* __restrict__ cam_gamma,
    const void* __restrict__ pam_wl, const void* __restrict__ pam_bl, const void* __restrict__ pam_gamma,
    ushort* __restrict__ Wfull, float* __restrict__ biasv, const int* __restrict__ flagp)
{
  int isbf = *flagp;
  int b = blockIdx.x, t = threadIdx.x;
  __shared__ float Atot[64][65];   // +1 pad: row-strided access -> 2 lanes/bank
  __shared__ float erow[64][65];
  int r = t >> 2, q = t & 3;       // row, quad-id (16 cols each)
#pragma unroll
  for (int j = 0; j < 16; ++j) Atot[r][q * 16 + j] = 0.f;
  // no sync needed: same (r,q) threads accumulate their own cells below
  for (int k = 0; k < 3; ++k) {
    const float* ep = e_red + (size_t)(b * 3 + k) * 4096;
    for (int i = t; i < 4096; i += 256) erow[i >> 6][i & 63] = ep[i];
    __syncthreads();
    float ev[16];
    float mn = 1e30f;
#pragma unroll
    for (int j = 0; j < 16; ++j) { ev[j] = erow[r][q * 16 + j]; mn = fminf(mn, ev[j]); }
    mn = fminf(mn, __shfl_xor(mn, 1, 64));
    mn = fminf(mn, __shfl_xor(mn, 2, 64));
    float s = 0.f;
#pragma unroll
    for (int j = 0; j < 16; ++j) { ev[j] = __expf(mn - ev[j]); s += ev[j]; }
    s += __shfl_xor(s, 1, 64);
    s += __shfl_xor(s, 2, 64);
    float inv = 1.0f / s;
#pragma unroll
    for (int j = 0; j < 16; ++j) Atot[r][q * 16 + j] += ev[j] * inv;
    __syncthreads();
  }
  float gc = loadf(cam_gamma, 0, isbf), gp = loadf(pam_gamma, 0, isbf);
  int c = t >> 2, d0 = (t & 3) * 16;
  float a[16];
#pragma unroll
  for (int i = 0; i < 16; ++i) a[i] = 0.f;
  for (int e = 0; e < 64; ++e) {
    float wv = loadf(cam_wl, c * 64 + e, isbf);
#pragma unroll
    for (int i = 0; i < 16; ++i) a[i] += wv * Atot[e][d0 + i];
  }
#pragma unroll
  for (int i = 0; i < 16; ++i) {
    int d = d0 + i;
    Wfull[(size_t)(b * 64 + c) * 128 + d]      = f2bf(gc * a[i]);
    Wfull[(size_t)(b * 64 + c) * 128 + 64 + d] = f2bf(gp * loadf(pam_wl, c * 64 + d, isbf));
  }
  if (b == 0 && t < 64) biasv[t] = gp * loadf(pam_bl, t, isbf) + gc * loadf(cam_bl, t, isbf);
}

// ---------------------------------------------------------------------------
// K6: PAM pass 2 — pam_part[b][ms][c][n] = sum_{m slice} V[c,m]*P[m,n],
//     P = sum_br exp2(Ehat_br - L_br) via L-slots in QT/KT. 1024 blocks (n-tile 32).
__global__ __launch_bounds__(256) void k_pam_out(
    const ushort* __restrict__ QT, const ushort* __restrict__ KT, const ushort* __restrict__ V,
    ushort* __restrict__ pam_part)
{
  __shared__ ushort plds[32 * 64];   // [n 32][m 64], XOR-swizzled rows
  int blk = blockIdx.x;
  int ms = blk & 3, nt = (blk >> 2) & 127, b = blk >> 9;
  int w = threadIdx.x >> 6, l = threadIdx.x & 63;
  int l15 = l & 15, lh = l >> 4;
  int n0 = nt * 32;

  bf16x8 kf[3][2];
#pragma unroll
  for (int br = 0; br < 3; ++br)
#pragma unroll
    for (int n16 = 0; n16 < 2; ++n16)
      kf[br][n16] = *(const bf16x8*)(KT + (size_t)((b * 3 + br) * 4096 + n0 + n16 * 16 + l15) * 32 + lh * 8);

  f32x4 acc[2];
  acc[0] = (f32x4){0.f, 0.f, 0.f, 0.f};
  acc[1] = (f32x4){0.f, 0.f, 0.f, 0.f};
  const ushort* Vb = V + (size_t)(b * 64 + 16 * w + l15) * 4096;

  for (int ch = 0; ch < 16; ++ch) {
    int mch = ms * 1024 + ch * 64;
    bf16x8 qf = *(const bf16x8*)(QT + (size_t)(b * 4096 + mch + 16 * w + l15) * 32 + lh * 8);
#pragma unroll
    for (int n16 = 0; n16 < 2; ++n16) {
      f32x4 d0 = MFMA16(qf, kf[0][n16], ((f32x4){0.f, 0.f, 0.f, 0.f}));
      f32x4 d1 = MFMA16(qf, kf[1][n16], ((f32x4){0.f, 0.f, 0.f, 0.f}));
      f32x4 d2 = MFMA16(qf, kf[2][n16], ((f32x4){0.f, 0.f, 0.f, 0.f}));
      unsigned int u0, u1;
      {
        float p0 = EX2(d0[0]) + EX2(d1[0]) + EX2(d2[0]);
        float p1 = EX2(d0[1]) + EX2(d1[1]) + EX2(d2[1]);
        float p2 = EX2(d0[2]) + EX2(d1[2]) + EX2(d2[2]);
        float p3 = EX2(d0[3]) + EX2(d1[3]) + EX2(d2[3]);
        u0 = (unsigned int)f2bf(p0) | ((unsigned int)f2bf(p1) << 16);
        u1 = (unsigned int)f2bf(p2) | ((unsigned int)f2bf(p3) << 16);
      }
      int nl = n16 * 16 + l15;
      int byte = (nl * 128 + (16 * w + lh * 4) * 2) ^ ((nl & 7) << 4);
      *(uint2*)((char*)plds + byte) = make_uint2(u0, u1);
    }
    __syncthreads();
#pragma unroll
    for (int ks = 0; ks < 2; ++ks) {
      bf16x8 vf = *(const bf16x8*)(Vb + mch + ks * 32 + lh * 8);
#pragma unroll
      for (int n16 = 0; n16 < 2; ++n16) {
        int nl = n16 * 16 + l15;
        int byte = (nl * 128 + (ks * 32 + lh * 8) * 2) ^ ((nl & 7) << 4);
        bf16x8 pf = *(const bf16x8*)((const char*)plds + byte);
        acc[n16] = MFMA16(vf, pf, acc[n16]);
      }
    }
    __syncthreads();
  }
  ushort* outp = pam_part + (size_t)((b * 4 + ms) * 64) * 4096;
#pragma unroll
  for (int n16 = 0; n16 < 2; ++n16)
#pragma unroll
    for (int r = 0; r < 4; ++r) {
      int c = 16 * w + lh * 4 + r, n = n0 + n16 * 16 + l15;
      outp[(size_t)c * 4096 + n] = f2bf(acc[n16][r]);
    }
}

// ---------------------------------------------------------------------------
// K7: final — out = 2x + M_b*x + (gp*Wp)*pam_out + biasv.
__global__ __launch_bounds__(256) void k_final(
    const void* __restrict__ x, const ushort* __restrict__ pam_part,
    const ushort* __restrict__ Wfull, const float* __restrict__ biasv,
    void* __restrict__ outv, const int* __restrict__ flagp)
{
  int isbf = *flagp;
  __shared__ ushort u[64 * 128];
  int blk = blockIdx.x;
  int nt = blk & 63, b = blk >> 6;
  int t = threadIdx.x;
  int n0 = nt * 64;
  int d = t >> 2, nl0 = (t & 3) * 16;
  size_t xbase = (size_t)(b * 64 + d) * 4096 + n0 + nl0;
#pragma unroll
  for (int i = 0; i < 16; ++i) {
    int nl = nl0 + i;
    int byte = (nl * 256 + d * 2) ^ ((nl & 7) << 4);
    *(ushort*)((char*)u + byte) = f2bf(loadf(x, xbase + i, isbf));
  }
  const ushort* pp = pam_part + (size_t)(b * 256 + d) * 4096 + n0 + nl0;
#pragma unroll
  for (int i = 0; i < 16; ++i) {
    float s = bf2f(pp[i]) + bf2f(pp[262144 + i]) + bf2f(pp[524288 + i]) + bf2f(pp[786432 + i]);
    int nl = nl0 + i;
    int byte = (nl * 256 + (64 + d) * 2) ^ ((nl & 7) << 4);
    *(ushort*)((char*)u + byte) = f2bf(s);
  }
  __syncthreads();

  int w = t >> 6, l = t & 63, l15 = l & 15, lh = l >> 4;
  f32x4 acc[4];
#pragma unroll
  for (int i = 0; i < 4; ++i) acc[i] = (f32x4){0.f, 0.f, 0.f, 0.f};
#pragma unroll
  for (int ks = 0; ks < 4; ++ks) {
    bf16x8 af = *(const bf16x8*)(Wfull + (size_t)(b * 64 + 16 * w + l15) * 128 + ks * 32 + lh * 8);
#pragma unroll
    for (int nt4 = 0; nt4 < 4; ++nt4) {
      int nl = nt4 * 16 + l15;
      int byte = (nl * 256 + (ks * 32 + lh * 8) * 2) ^ ((nl & 7) << 4);
      bf16x8 bfr = *(const bf16x8*)((const char*)u + byte);
      acc[nt4] = MFMA16(af, bfr, acc[nt4]);
    }
  }
#pragma unroll
  for (int nt4 = 0; nt4 < 4; ++nt4)
#pragma unroll
    for (int r = 0; r < 4; ++r) {
      int c = 16 * w + lh * 4 + r, nl = nt4 * 16 + l15;
      size_t xidx = (size_t)(b * 64 + c) * 4096 + n0 + nl;
      float xv = loadf(x, xidx, isbf);
      float v = acc[nt4][r] + 2.0f * xv + biasv[c];
      if (isbf) ((ushort*)outv)[xidx] = f2bf(v);
      else      ((float*)outv)[xidx]  = v;
    }
}

// ---------------------------------------------------------------------------
extern "C" void kernel_launch(void* const* d_in, const int* in_sizes, int n_in,
                              void* d_out, int out_size, void* d_ws, size_t ws_size,
                              hipStream_t stream) {
  const void* x   = d_in[0];
  const void* y   = d_in[1];
  const void* z   = d_in[2];
  const void* wq  = d_in[3];
  const void* bq  = d_in[4];
  const void* wk1 = d_in[5];
  const void* bk1 = d_in[6];
  const void* wk2 = d_in[7];
  const void* bk2 = d_in[8];
  const void* wk3 = d_in[9];
  const void* bk3 = d_in[10];
  const void* wv  = d_in[11];
  const void* bv  = d_in[12];
  const void* pwl = d_in[13];
  const void* pbl = d_in[14];
  const void* pg  = d_in[15];
  const void* cwl = d_in[16];
  const void* cbl = d_in[17];
  const void* cg  = d_in[18];

  char* ws = (char*)d_ws;
  int*    flag    = (int*)   (ws + 0);          //  4 B (pad 256)
  ushort* QT      = (ushort*)(ws + 256);        //  512 KB  [2][4096][32] bf16
  ushort* KT      = (ushort*)(ws + 524544);     // 1536 KB  [6][4096][32] bf16
  ushort* V       = (ushort*)(ws + 2097408);    // 1024 KB  [2][64][4096] bf16
  float*  S_part  = (float*) (ws + 3145984);    //  384 KB  [4][2*3*4096] f32
  float*  e_part  = (float*) (ws + 3539200);    // 1536 KB  [2][3][16][64][64] f32
  ushort* pam_prt = (ushort*)(ws + 5112064);    // 4096 KB  [2][4][64][4096] bf16
  ushort* Wfull   = (ushort*)(ws + 9306368);    //   32 KB  [2][64][128] bf16
  float*  biasv   = (float*) (ws + 9339136);    //  256 B   [64] f32
  float*  e_red   = (float*) (ws + 9339392);    //   96 KB  [2][3][64][64] f32

  k_detect    <<<   1,  64, 0, stream>>>((const unsigned int*)x, flag);
  k_prep_qk   <<< 128, 256, 0, stream>>>(x, y, z, wq, bq, wk1, bk1, wk2, bk2, wk3, bk3, QT, KT, flag);
  k_prep_v    <<<2048, 256, 0, stream>>>(x, wv, bv, V, flag);
  k_cam_gram  <<<  96, 256, 0, stream>>>(x, y, z, e_part, flag);
  k_pam_s     <<<1536, 256, 0, stream>>>(QT, KT, S_part);
  k_s_final   <<<  96, 256, 0, stream>>>(S_part, QT);
  k_cam_reduce<<<  96, 256, 0, stream>>>(e_part, e_red);
  k_cam_small <<<   2, 256, 0, stream>>>(e_red, cwl, cbl, cg, pwl, pbl, pg, Wfull, biasv, flag);
  k_pam_out   <<<1024, 256, 0, stream>>>(QT, KT, V, pam_prt);
  k_final     <<< 128, 256, 0, stream>>>(x, pam_prt, Wfull, biasv, d_out, flag);
}

// Round 5
// 100.181 us; speedup vs baseline: 2.3056x; 1.3175x over previous
//
#include <hip/hip_runtime.h>
#include <hip/hip_bf16.h>

// MsPAM+CAM fused, MI355X gfx950.  B=2, C=64, H=W=64, N=4096, Cq=8.
// 5-kernel pipeline, per-block runtime dtype detect, softmax normalization
// folded into MFMA via spare Q/K slots (Q 8..13 = -log2(S), K one-hot 1.0).

typedef __attribute__((ext_vector_type(8))) short bf16x8;
typedef __attribute__((ext_vector_type(4))) float f32x4;

#define MFMA16(a, b, c) __builtin_amdgcn_mfma_f32_16x16x32_bf16(a, b, c, 0, 0, 0)
#define EX2(x) __builtin_amdgcn_exp2f(x)
#define LOG2E 1.4426950408889634f

__device__ __forceinline__ float bf2f(ushort u) {
  union { unsigned int i; float f; } v; v.i = ((unsigned int)u) << 16; return v.f;
}
__device__ __forceinline__ ushort f2bf(float f) {  // RNE
  union { float f; unsigned int i; } v; v.f = f;
  unsigned int r = v.i + 0x7FFFu + ((v.i >> 16) & 1u);
  return (ushort)(r >> 16);
}
__device__ __forceinline__ float loadf(const void* p, size_t i, int isbf) {
  return isbf ? bf2f(((const ushort*)p)[i]) : ((const float*)p)[i];
}
__device__ __forceinline__ bf16x8 load8(const void* p, size_t i, int isbf) {
  if (isbf) return *(const bf16x8*)((const ushort*)p + i);
  const float* f = (const float*)p + i;
  bf16x8 r;
#pragma unroll
  for (int j = 0; j < 8; ++j) r[j] = (short)f2bf(f[j]);
  return r;
}
__device__ __forceinline__ void loadf8(const void* p, size_t i, int isbf, float* o) {
  if (isbf) {
    bf16x8 v = *(const bf16x8*)((const ushort*)p + i);
#pragma unroll
    for (int j = 0; j < 8; ++j) o[j] = bf2f((ushort)v[j]);
  } else {
    const float* f = (const float*)p + i;
#pragma unroll
    for (int j = 0; j < 8; ++j) o[j] = f[j];
  }
}
// per-block dtype detect: bf16-packed x has low-16 exponent bits in [120,133].
__device__ __forceinline__ int detect_isbf(const unsigned int* xw, int* sflag) {
  int t = threadIdx.x;
  if (t < 64) {
    unsigned int w1 = xw[t], w2 = xw[64 + t];
    unsigned int e1 = (w1 >> 7) & 0xFFu, e2 = (w2 >> 7) & 0xFFu;
    unsigned long long b1 = __ballot(e1 >= 120u && e1 <= 133u);
    unsigned long long b2 = __ballot(e2 >= 120u && e2 <= 133u);
    if (t == 0) *sflag = (__popcll(b1) + __popcll(b2) > 64) ? 1 : 0;
  }
  __syncthreads();
  return *sflag;
}

// ---------------------------------------------------------------------------
// KA: fused prep. blocks 0..127: Q/K convs -> QT/KT; 128..383: V conv;
//     384..479: CAM gram partials e_part.
__global__ __launch_bounds__(256) void k_prep_all(
    const void* __restrict__ x, const void* __restrict__ y, const void* __restrict__ z,
    const void* __restrict__ wq, const void* __restrict__ bq,
    const void* __restrict__ wk1, const void* __restrict__ bk1,
    const void* __restrict__ wk2, const void* __restrict__ bk2,
    const void* __restrict__ wk3, const void* __restrict__ bk3,
    const void* __restrict__ wv, const void* __restrict__ bv,
    ushort* __restrict__ QT, ushort* __restrict__ KT, ushort* __restrict__ V,
    float* __restrict__ e_part)
{
  __shared__ float wsh[4][8][64];
  __shared__ int sflag;
  int isbf = detect_isbf((const unsigned int*)x, &sflag);
  int blk = blockIdx.x, t = threadIdx.x;

  if (blk < 128) {
    // ---- Q/K1/K2/K3 convs, 4 threads per n (16 c each) + quad shfl reduce
    for (int i = t; i < 2048; i += 256) {
      int mat = i >> 9, rem = i & 511;
      const void* src = (mat == 0) ? wq : (mat == 1) ? wk1 : (mat == 2) ? wk2 : wk3;
      wsh[mat][rem >> 6][rem & 63] = loadf(src, rem, isbf);
    }
    __syncthreads();
    int gid = blk * 256 + t;            // 0..32767
    int qid = gid & 3;
    int n = (gid >> 2) & 4095;
    int b = gid >> 14;
    int c0 = qid * 16;
    float a[4][8];
#pragma unroll
    for (int m = 0; m < 4; ++m)
#pragma unroll
      for (int o = 0; o < 8; ++o) a[m][o] = 0.f;
    size_t base = (size_t)b * 262144 + n;
    for (int cc = 0; cc < 16; ++cc) {
      int c = c0 + cc;
      float xv = loadf(x, base + (size_t)c * 4096, isbf);
      float yv = loadf(y, base + (size_t)c * 4096, isbf);
      float zv = loadf(z, base + (size_t)c * 4096, isbf);
#pragma unroll
      for (int o = 0; o < 8; ++o) {
        a[0][o] += wsh[0][o][c] * xv;
        a[1][o] += wsh[1][o][c] * xv;
        a[2][o] += wsh[2][o][c] * yv;
        a[3][o] += wsh[3][o][c] * zv;
      }
    }
#pragma unroll
    for (int m = 0; m < 4; ++m)
#pragma unroll
      for (int o = 0; o < 8; ++o) {
        float v = a[m][o];
        v += __shfl_xor(v, 1, 64);
        v += __shfl_xor(v, 2, 64);
        a[m][o] = v;
      }
    int br = qid - 1;
    const void* bias = (qid == 0) ? bq : (qid == 1) ? bk1 : (qid == 2) ? bk2 : bk3;
    ushort* dst = (qid == 0) ? QT + (size_t)(b * 4096 + n) * 32
                             : KT + (size_t)((b * 3 + br) * 4096 + n) * 32;
    ushort row[32];
#pragma unroll
    for (int o = 0; o < 8; ++o) {
      float v = a[qid][o] + loadf(bias, o, isbf);
      row[o] = f2bf(qid == 0 ? LOG2E * v : v);
    }
#pragma unroll
    for (int o = 8; o < 32; ++o)
      row[o] = (qid > 0 && (o == 8 + 2 * br || o == 9 + 2 * br)) ? (ushort)0x3F80 : (ushort)0;
#pragma unroll
    for (int o = 0; o < 32; o += 2)
      *(unsigned int*)(dst + o) = (unsigned int)row[o] | ((unsigned int)row[o + 1] << 16);
  } else if (blk < 384) {
    // ---- V = wv*x + bv, 8 outputs per thread
    int tid2 = (blk - 128) * 256 + t;   // 0..65535
    int b = tid2 >> 15, c = (tid2 >> 9) & 63, m0 = (tid2 & 511) * 8;
    float acc[8], xv[8];
    float bb = loadf(bv, c, isbf);
#pragma unroll
    for (int j = 0; j < 8; ++j) acc[j] = bb;
    size_t xb = (size_t)b * 262144 + m0;
    for (int d = 0; d < 64; ++d) {
      float w = loadf(wv, c * 64 + d, isbf);
      loadf8(x, xb + (size_t)d * 4096, isbf, xv);
#pragma unroll
      for (int j = 0; j < 8; ++j) acc[j] += w * xv[j];
    }
    bf16x8 o8;
#pragma unroll
    for (int j = 0; j < 8; ++j) o8[j] = (short)f2bf(acc[j]);
    *(bf16x8*)(V + (size_t)(b * 64 + c) * 4096 + m0) = o8;
  } else {
    // ---- CAM gram partials e_part[b][k][ns16][64][64]
    int r2 = blk - 384;
    int ns = r2 & 15, r = r2 >> 4;      // r in 0..5
    int k = r % 3, b = r / 3;
    const void* A = x;
    const void* B = (k == 0) ? x : (k == 1) ? y : z;
    size_t boff = (size_t)b * 262144;
    int w = t >> 6, l = t & 63;
    int l15 = l & 15, lh = l >> 4;
    int cbase = 16 * w;
    f32x4 acc[4];
#pragma unroll
    for (int i = 0; i < 4; ++i) acc[i] = (f32x4){0.f, 0.f, 0.f, 0.f};
    int n0 = ns * 256;
    for (int step = 0; step < 8; ++step) {
      int nb = n0 + step * 32;
      bf16x8 af = load8(A, boff + (size_t)(cbase + l15) * 4096 + nb + lh * 8, isbf);
#pragma unroll
      for (int dt = 0; dt < 4; ++dt) {
        bf16x8 bfr = load8(B, boff + (size_t)(dt * 16 + l15) * 4096 + nb + lh * 8, isbf);
        acc[dt] = MFMA16(af, bfr, acc[dt]);
      }
    }
    float* out = e_part + (size_t)(((b * 3 + k) * 16 + ns) * 64) * 64;
#pragma unroll
    for (int dt = 0; dt < 4; ++dt)
#pragma unroll
      for (int rr = 0; rr < 4; ++rr) {
        int c = cbase + lh * 4 + rr, d = dt * 16 + l15;
        out[c * 64 + d] = acc[dt][rr];
      }
  }
}

// ---------------------------------------------------------------------------
// KB: blocks 0..1535: PAM pass 1 S_part; 1536..1631: reduce e_part -> e_red.
__global__ __launch_bounds__(256) void k_pass1(
    const ushort* __restrict__ QT, const ushort* __restrict__ KT,
    const float* __restrict__ e_part, float* __restrict__ S_part, float* __restrict__ e_red)
{
  int blk = blockIdx.x, t = threadIdx.x;
  if (blk < 1536) {
    int sl = blk & 3, mc = (blk >> 2) & 63, r3 = blk >> 8;  // r3 in 0..5
    int br = r3 % 3, b = r3 / 3;
    int w = t >> 6, l = t & 63;
    int l15 = l & 15, lh = l >> 4;
    int mbase = mc * 64 + w * 16;
    bf16x8 qf = *(const bf16x8*)(QT + (size_t)(b * 4096 + mbase + l15) * 32 + lh * 8);
    const ushort* Kb = KT + (size_t)((b * 3 + br) * 4096) * 32;
    float s = 0.f;
    int ns0 = sl * 64;
#pragma unroll 4
    for (int ns = ns0; ns < ns0 + 64; ++ns) {
      bf16x8 kf = *(const bf16x8*)(Kb + (size_t)(ns * 16 + l15) * 32 + lh * 8);
      f32x4 d = MFMA16(kf, qf, ((f32x4){0.f, 0.f, 0.f, 0.f}));
      s += EX2(d[0]) + EX2(d[1]) + EX2(d[2]) + EX2(d[3]);
    }
    s += __shfl_xor(s, 16, 64);
    s += __shfl_xor(s, 32, 64);
    if (l < 16) S_part[sl * 24576 + (b * 3 + br) * 4096 + mbase + l] = s;
  } else {
    int i = (blk - 1536) * 256 + t;     // 24576
    const float* p = e_part + (size_t)(i >> 12) * 65536 + (i & 4095);
    float s = 0.f;
#pragma unroll
    for (int ks = 0; ks < 16; ++ks) s += p[ks * 4096];
    e_red[i] = s;
  }
}

// ---------------------------------------------------------------------------
// KC: blocks 0..95: S finalize -> QT L-slots; 96..97: CAM small matmul.
__global__ __launch_bounds__(256) void k_mid(
    const float* __restrict__ S_part, ushort* __restrict__ QT,
    const float* __restrict__ e_red, const void* __restrict__ x,
    const void* __restrict__ cam_wl, const void* __restrict__ cam_bl, const void* __restrict__ cam_gamma,
    const void* __restrict__ pam_wl, const void* __restrict__ pam_bl, const void* __restrict__ pam_gamma,
    ushort* __restrict__ Wfull, float* __restrict__ biasv)
{
  int blk = blockIdx.x, t = threadIdx.x;
  if (blk < 96) {
    int i = blk * 256 + t;              // 24576
    float S = S_part[i] + S_part[24576 + i] + S_part[49152 + i] + S_part[73728 + i];
    float nL = -__builtin_amdgcn_logf(S);  // -log2(S)
    int m = i & 4095, b3br = i >> 12;
    int br = b3br % 3, b = b3br / 3;
    ushort c = f2bf(nL);
    ushort r = f2bf(nL - bf2f(c));
    ushort* qrow = QT + (size_t)(b * 4096 + m) * 32;
    qrow[8 + 2 * br] = c;
    qrow[9 + 2 * br] = r;
  } else {
    __shared__ float Atot[64][65];
    __shared__ float erow[64][65];
    __shared__ int sflag;
    int isbf = detect_isbf((const unsigned int*)x, &sflag);
    int b = blk - 96;
    int r = t >> 2, q = t & 3;
#pragma unroll
    for (int j = 0; j < 16; ++j) Atot[r][q * 16 + j] = 0.f;
    for (int k = 0; k < 3; ++k) {
      const float* ep = e_red + (size_t)(b * 3 + k) * 4096;
      for (int i = t; i < 4096; i += 256) erow[i >> 6][i & 63] = ep[i];
      __syncthreads();
      float ev[16];
      float mn = 1e30f;
#pragma unroll
      for (int j = 0; j < 16; ++j) { ev[j] = erow[r][q * 16 + j]; mn = fminf(mn, ev[j]); }
      mn = fminf(mn, __shfl_xor(mn, 1, 64));
      mn = fminf(mn, __shfl_xor(mn, 2, 64));
      float s = 0.f;
#pragma unroll
      for (int j = 0; j < 16; ++j) { ev[j] = __expf(mn - ev[j]); s += ev[j]; }
      s += __shfl_xor(s, 1, 64);
      s += __shfl_xor(s, 2, 64);
      float inv = 1.0f / s;
#pragma unroll
      for (int j = 0; j < 16; ++j) Atot[r][q * 16 + j] += ev[j] * inv;
      __syncthreads();
    }
    float gc = loadf(cam_gamma, 0, isbf), gp = loadf(pam_gamma, 0, isbf);
    int c = t >> 2, d0 = (t & 3) * 16;
    float a[16];
#pragma unroll
    for (int i = 0; i < 16; ++i) a[i] = 0.f;
    for (int e = 0; e < 64; ++e) {
      float wv = loadf(cam_wl, c * 64 + e, isbf);
#pragma unroll
      for (int i = 0; i < 16; ++i) a[i] += wv * Atot[e][d0 + i];
    }
#pragma unroll
    for (int i = 0; i < 16; ++i) {
      int d = d0 + i;
      Wfull[(size_t)(b * 64 + c) * 128 + d]      = f2bf(gc * a[i]);
      Wfull[(size_t)(b * 64 + c) * 128 + 64 + d] = f2bf(gp * loadf(pam_wl, c * 64 + d, isbf));
    }
    if (b == 0 && t < 64) biasv[t] = gp * loadf(pam_bl, t, isbf) + gc * loadf(cam_bl, t, isbf);
  }
}

// ---------------------------------------------------------------------------
// KD: PAM pass 2 — pam_part[b][ms][c][n] = sum_{m slice} V[c,m]*P[m,n],
//     P = sum_br exp2(Ehat_br - L_br). Ping-pong LDS, 1 barrier/chunk. 1024 blocks.
__global__ __launch_bounds__(256) void k_pam_out(
    const ushort* __restrict__ QT, const ushort* __restrict__ KT, const ushort* __restrict__ V,
    ushort* __restrict__ pam_part)
{
  __shared__ ushort plds[2][32 * 64];
  int blk = blockIdx.x;
  int ms = blk & 3, nt = (blk >> 2) & 127, b = blk >> 9;
  int w = threadIdx.x >> 6, l = threadIdx.x & 63;
  int l15 = l & 15, lh = l >> 4;
  int n0 = nt * 32;

  bf16x8 kf[3][2];
#pragma unroll
  for (int br = 0; br < 3; ++br)
#pragma unroll
    for (int n16 = 0; n16 < 2; ++n16)
      kf[br][n16] = *(const bf16x8*)(KT + (size_t)((b * 3 + br) * 4096 + n0 + n16 * 16 + l15) * 32 + lh * 8);

  f32x4 acc[2];
  acc[0] = (f32x4){0.f, 0.f, 0.f, 0.f};
  acc[1] = (f32x4){0.f, 0.f, 0.f, 0.f};
  const ushort* Vb = V + (size_t)(b * 64 + 16 * w + l15) * 4096;

  for (int ch = 0; ch < 16; ++ch) {
    int mch = ms * 1024 + ch * 64;
    char* buf = (char*)plds[ch & 1];
    bf16x8 qf = *(const bf16x8*)(QT + (size_t)(b * 4096 + mch + 16 * w + l15) * 32 + lh * 8);
#pragma unroll
    for (int n16 = 0; n16 < 2; ++n16) {
      f32x4 d0 = MFMA16(qf, kf[0][n16], ((f32x4){0.f, 0.f, 0.f, 0.f}));
      f32x4 d1 = MFMA16(qf, kf[1][n16], ((f32x4){0.f, 0.f, 0.f, 0.f}));
      f32x4 d2 = MFMA16(qf, kf[2][n16], ((f32x4){0.f, 0.f, 0.f, 0.f}));
      float p0 = EX2(d0[0]) + EX2(d1[0]) + EX2(d2[0]);
      float p1 = EX2(d0[1]) + EX2(d1[1]) + EX2(d2[1]);
      float p2 = EX2(d0[2]) + EX2(d1[2]) + EX2(d2[2]);
      float p3 = EX2(d0[3]) + EX2(d1[3]) + EX2(d2[3]);
      unsigned int u0, u1;
      asm("v_cvt_pk_bf16_f32 %0, %1, %2" : "=v"(u0) : "v"(p0), "v"(p1));
      asm("v_cvt_pk_bf16_f32 %0, %1, %2" : "=v"(u1) : "v"(p2), "v"(p3));
      int nl = n16 * 16 + l15;
      int byte = (nl * 128 + (16 * w + lh * 4) * 2) ^ ((nl & 7) << 4);
      *(uint2*)(buf + byte) = make_uint2(u0, u1);
    }
    __syncthreads();
#pragma unroll
    for (int ks = 0; ks < 2; ++ks) {
      bf16x8 vf = *(const bf16x8*)(Vb + mch + ks * 32 + lh * 8);
#pragma unroll
      for (int n16 = 0; n16 < 2; ++n16) {
        int nl = n16 * 16 + l15;
        int byte = (nl * 128 + (ks * 32 + lh * 8) * 2) ^ ((nl & 7) << 4);
        bf16x8 pf = *(const bf16x8*)((const char*)buf + byte);
        acc[n16] = MFMA16(vf, pf, acc[n16]);
      }
    }
    // no trailing barrier: next chunk writes the OTHER buffer; the next
    // barrier orders this chunk's reads before that buffer's 2nd-next reuse.
  }
  ushort* outp = pam_part + (size_t)((b * 4 + ms) * 64) * 4096;
#pragma unroll
  for (int n16 = 0; n16 < 2; ++n16)
#pragma unroll
    for (int r = 0; r < 4; ++r) {
      int c = 16 * w + lh * 4 + r, n = n0 + n16 * 16 + l15;
      outp[(size_t)c * 4096 + n] = f2bf(acc[n16][r]);
    }
}

// ---------------------------------------------------------------------------
// KE: final — out = 2x + M_b*x + (gp*Wp)*pam_out + biasv. 128 blocks.
__global__ __launch_bounds__(256) void k_final(
    const void* __restrict__ x, const ushort* __restrict__ pam_part,
    const ushort* __restrict__ Wfull, const float* __restrict__ biasv,
    void* __restrict__ outv)
{
  __shared__ ushort u[64 * 128];
  __shared__ int sflag;
  int isbf = detect_isbf((const unsigned int*)x, &sflag);
  int blk = blockIdx.x;
  int nt = blk & 63, b = blk >> 6;
  int t = threadIdx.x;
  int n0 = nt * 64;
  int d = t >> 2, nl0 = (t & 3) * 16;
  size_t xbase = (size_t)(b * 64 + d) * 4096 + n0 + nl0;
#pragma unroll
  for (int i = 0; i < 16; ++i) {
    int nl = nl0 + i;
    int byte = (nl * 256 + d * 2) ^ ((nl & 7) << 4);
    *(ushort*)((char*)u + byte) = f2bf(loadf(x, xbase + i, isbf));
  }
  const ushort* pp = pam_part + (size_t)(b * 256 + d) * 4096 + n0 + nl0;
#pragma unroll
  for (int i = 0; i < 16; ++i) {
    float s = bf2f(pp[i]) + bf2f(pp[262144 + i]) + bf2f(pp[524288 + i]) + bf2f(pp[786432 + i]);
    int nl = nl0 + i;
    int byte = (nl * 256 + (64 + d) * 2) ^ ((nl & 7) << 4);
    *(ushort*)((char*)u + byte) = f2bf(s);
  }
  __syncthreads();

  int w = t >> 6, l = t & 63, l15 = l & 15, lh = l >> 4;
  f32x4 acc[4];
#pragma unroll
  for (int i = 0; i < 4; ++i) acc[i] = (f32x4){0.f, 0.f, 0.f, 0.f};
#pragma unroll
  for (int ks = 0; ks < 4; ++ks) {
    bf16x8 af = *(const bf16x8*)(Wfull + (size_t)(b * 64 + 16 * w + l15) * 128 + ks * 32 + lh * 8);
#pragma unroll
    for (int nt4 = 0; nt4 < 4; ++nt4) {
      int nl = nt4 * 16 + l15;
      int byte = (nl * 256 + (ks * 32 + lh * 8) * 2) ^ ((nl & 7) << 4);
      bf16x8 bfr = *(const bf16x8*)((const char*)u + byte);
      acc[nt4] = MFMA16(af, bfr, acc[nt4]);
    }
  }
#pragma unroll
  for (int nt4 = 0; nt4 < 4; ++nt4)
#pragma unroll
    for (int r = 0; r < 4; ++r) {
      int c = 16 * w + lh * 4 + r, nl = nt4 * 16 + l15;
      size_t xidx = (size_t)(b * 64 + c) * 4096 + n0 + nl;
      float xv = loadf(x, xidx, isbf);
      float v = acc[nt4][r] + 2.0f * xv + biasv[c];
      if (isbf) ((ushort*)outv)[xidx] = f2bf(v);
      else      ((float*)outv)[xidx]  = v;
    }
}

// ---------------------------------------------------------------------------
extern "C" void kernel_launch(void* const* d_in, const int* in_sizes, int n_in,
                              void* d_out, int out_size, void* d_ws, size_t ws_size,
                              hipStream_t stream) {
  const void* x   = d_in[0];
  const void* y   = d_in[1];
  const void* z   = d_in[2];
  const void* wq  = d_in[3];
  const void* bq  = d_in[4];
  const void* wk1 = d_in[5];
  const void* bk1 = d_in[6];
  const void* wk2 = d_in[7];
  const void* bk2 = d_in[8];
  const void* wk3 = d_in[9];
  const void* bk3 = d_in[10];
  const void* wv  = d_in[11];
  const void* bv  = d_in[12];
  const void* pwl = d_in[13];
  const void* pbl = d_in[14];
  const void* pg  = d_in[15];
  const void* cwl = d_in[16];
  const void* cbl = d_in[17];
  const void* cg  = d_in[18];

  char* ws = (char*)d_ws;
  ushort* QT      = (ushort*)(ws + 0);         //  512 KB  [2][4096][32] bf16
  ushort* KT      = (ushort*)(ws + 524288);    // 1536 KB  [6][4096][32] bf16
  ushort* V       = (ushort*)(ws + 2097152);   // 1024 KB  [2][64][4096] bf16
  float*  S_part  = (float*) (ws + 3145728);   //  384 KB  [4][2*3*4096] f32
  float*  e_part  = (float*) (ws + 3538944);   // 1536 KB  [2][3][16][64][64] f32
  ushort* pam_prt = (ushort*)(ws + 5111808);   // 4096 KB  [2][4][64][4096] bf16
  ushort* Wfull   = (ushort*)(ws + 9306112);   //   32 KB  [2][64][128] bf16
  float*  biasv   = (float*) (ws + 9338880);   //  256 B   [64] f32
  float*  e_red   = (float*) (ws + 9339136);   //   96 KB  [2][3][64][64] f32

  k_prep_all<<< 480, 256, 0, stream>>>(x, y, z, wq, bq, wk1, bk1, wk2, bk2, wk3, bk3,
                                       wv, bv, QT, KT, V, e_part);
  k_pass1   <<<1632, 256, 0, stream>>>(QT, KT, e_part, S_part, e_red);
  k_mid     <<<  98, 256, 0, stream>>>(S_part, QT, e_red, x, cwl, cbl, cg, pwl, pbl, pg,
                                       Wfull, biasv);
  k_pam_out <<<1024, 256, 0, stream>>>(QT, KT, V, pam_prt);
  k_final   <<< 128, 256, 0, stream>>>(x, pam_prt, Wfull, biasv, d_out);
}